// Round 6
// baseline (1320.736 us; speedup 1.0000x reference)
//
#include <hip/hip_runtime.h>

// NearestEmbed (VQ argmin + gather), MI355X gfx950.  Round 6.
// x: (B=64, D=64, H=32, W=32) fp32 ; emb: (D=64, K=512) fp32
// out0: quant (B,D,H,W) fp32 ; out1: argmin (B,H,W) as fp32 values.
//
// R6 = merge of the two PROVEN halves:
//  * R3's scalar scan: rolled 8-chunk loop, float acc[16] const-indexed
//    (R3 measured clean: FETCH 8.8MB, WRITE 16.6MB, 0 conflicts), emb via
//    wave-uniform addresses -> s_load + SGPR-broadcast fma operands.
//  * R4/R5's LDS-staged x: xs[d][row], stride-1 ds_read_b32, 1 LDS read per
//    16 FMAs (LDS pipe ~3K cyc/wave vs 16.4K VALU cyc -> hidden).
// Dropped: packed v2 accumulators — R4 (FETCH 1.1GB) and R5 (WRITE 137MB,
// VGPR=64 = R4's alloca signature) both proved ext-vector accumulators get
// demoted to scratch by this compiler. Scalar floor: 2.147e9 lane-FMA /
// (1024 SIMD * 32 lanes) / 2.4GHz = 27.3 us.

constexpr int D  = 64;
constexpr int K  = 512;
constexpr int HW = 1024;       // 32*32
constexpr int RB = 64;         // rows per block

typedef float f4 __attribute__((ext_vector_type(4)));

__global__ __launch_bounds__(256, 6) void vq_argmin_kernel(
    const float* __restrict__ x,
    const float* __restrict__ emb,
    float* __restrict__ out_q,
    float* __restrict__ out_idx)
{
    __shared__ float xs[D * RB];       // 16 KB, [d][row]
    __shared__ float e2s[K];           // 2 KB
    __shared__ float mb[4][RB];
    __shared__ int   mi[4][RB];
    __shared__ int   kfin[RB];

    const int tid  = threadIdx.x;
    const int lane = tid & 63;                                   // block-local row
    const int wv   = __builtin_amdgcn_readfirstlane(tid >> 6);   // code quarter 0..3
    const int r0   = blockIdx.x * RB;
    const int b    = r0 >> 10;                                   // batch (no straddle)
    const int n0   = r0 & 1023;                                  // spatial base

    // --- ||e_k||^2 (coalesced; also warms L2 for the scalar emb loads) ---
    for (int k = tid; k < K; k += 256) {
        float s = 0.f;
        #pragma unroll 16
        for (int d = 0; d < D; ++d) { float v = emb[d * K + k]; s = fmaf(v, v, s); }
        e2s[k] = s;
    }

    // --- stage x tile [d][row] via float4 (n0 is 64-aligned => 16B-aligned) ---
    {
        const f4* xv4 = (const f4*)(x + (size_t)b * D * HW + n0);
        f4* xs4 = (f4*)xs;
        #pragma unroll
        for (int i = tid; i < D * RB / 4; i += 256) {    // 4 iters
            int d = i >> 4, c = i & 15;                  // 16 f4 per d-plane
            xs4[i] = xv4[d * (HW / 4) + c];
        }
    }
    __syncthreads();

    // --- this wave scans its 128-code quarter: 8 chunks of 16 codes ---
    float best = 3.4e38f;
    int   bidx = 0;
    const int kq = wv * 128;
    const float* xp = xs + lane;

    for (int g = 0; g < 8; ++g) {                  // rolled (R3-proven shape)
        const int k0 = kq + g * 16;
        const float* ep = emb + k0;                // wave-uniform base
        float acc[16];
        #pragma unroll
        for (int i = 0; i < 16; ++i) acc[i] = 0.f;

        #pragma unroll                              // full: acc[] const-indexed
        for (int d = 0; d < D; ++d) {
            const float xd = xp[d * RB];            // ds_read_b32, stride-1, 0-conflict
            #pragma unroll
            for (int i = 0; i < 16; ++i)
                acc[i] = fmaf(xd, ep[d * K + i], acc[i]);   // s_load + SGPR bcast
        }

        #pragma unroll
        for (int i = 0; i < 16; ++i) {
            float s = fmaf(-2.f, acc[i], e2s[k0 + i]);      // LDS broadcast
            if (s < best) { best = s; bidx = k0 + i; }      // strict <: first-index
        }
    }

    // --- 4-way quarter merge per row (ascending wv => lowest index on ties) ---
    mb[wv][lane] = best; mi[wv][lane] = bidx;
    __syncthreads();

    if (tid < RB) {
        float bb = mb[0][tid]; int bi = mi[0][tid];
        #pragma unroll
        for (int w = 1; w < 4; ++w) {
            float ob = mb[w][tid]; int oi = mi[w][tid];
            if (ob < bb) { bb = ob; bi = oi; }
        }
        kfin[tid] = bi;
        __builtin_nontemporal_store((float)bi, &out_idx[r0 + tid]);
    }
    __syncthreads();

    // --- epilogue: gather (emb L2-hot) + coalesced nontemporal stores ---
    for (int i = tid; i < D * RB; i += 256) {             // 16 iters
        int d = i >> 6, row = i & 63;
        __builtin_nontemporal_store(emb[d * K + kfin[row]],
                                    &out_q[(size_t)(b * D + d) * HW + n0 + row]);
    }
}

extern "C" void kernel_launch(void* const* d_in, const int* in_sizes, int n_in,
                              void* d_out, int out_size, void* d_ws, size_t ws_size,
                              hipStream_t stream)
{
    const float* x   = (const float*)d_in[0];   // 4194304 floats
    const float* emb = (const float*)d_in[1];   // 32768 floats

    float* out_q   = (float*)d_out;                     // 4194304 floats
    float* out_idx = out_q + (size_t)64 * 64 * 1024;    // 65536 floats

    // 65536 rows / 64 rows-per-block = 1024 blocks of 256 threads
    // (4 code-quarters per row per block); ~20.3 KB LDS -> up to 6-7 blocks/CU.
    vq_argmin_kernel<<<1024, 256, 0, stream>>>(x, emb, out_q, out_idx);
}

// Round 7
// 144.873 us; speedup vs baseline: 9.1165x; 9.1165x over previous
//
#include <hip/hip_runtime.h>

// NearestEmbed (VQ argmin + gather), MI355X gfx950.  Round 7.
// x: (B=64, D=64, H=32, W=32) fp32 ; emb: (D=64, K=512) fp32
// out0: quant (B,D,H,W) fp32 ; out1: argmin (B,H,W) as fp32 values.
//
// R7: role transpose. lanes = CODES, scalar path = X.
//  - Wave owns 16 consecutive rows; sweeps 512 codes in 8 sets of 64
//    (one code per lane).
//  - Per d-step: 1 coalesced global_load_dword (e-column, L2-hot) +
//    1 s_load_dwordx16 (x[d][n0..n0+16), wave-uniform, scalar-cache-hot)
//    + 16 v_fmac (SGPR x-operand, VGPR e-operand).  16 FMA : 2 mem ops.
//  - ||e||^2 computed in-line by each lane (acc2 += ev*ev): no LDS at all.
//  - Per-thread live regs: acc[16]+best[16]+bidx[16] ~ 60 VGPR; no 64-deep
//    array, no dynamic register indexing -> no scratch path (R4/5/6 lesson).
//  - Cross-lane argmin: 16 butterflies with explicit tie-break (lower idx),
//    matching numpy argmin first-occurrence semantics.
// Scalar fp32 floor: 2.147e9 lane-FMA / (1024 SIMD * 32 l/cyc) / 2.4GHz
// = 27.3 us (v_pk_fma_f32 is not faster: 157.3 TF spec == 1 FMA/lane/cyc).

constexpr int D   = 64;
constexpr int K   = 512;
constexpr int HW  = 1024;     // 32*32
constexpr int RPW = 16;       // rows per wave

__global__ __launch_bounds__(256, 4) void vq_argmin_kernel(
    const float* __restrict__ x,
    const float* __restrict__ emb,
    float* __restrict__ out_q,
    float* __restrict__ out_idx)
{
    const int tid  = threadIdx.x;
    const int lane = tid & 63;
    const int wv   = __builtin_amdgcn_readfirstlane(tid >> 6);   // wave id 0..3
    const int r0   = blockIdx.x * 64 + wv * RPW;   // first row of this wave
    const int b    = r0 >> 10;                     // batch (64 | 1024: no straddle)
    const int n0   = r0 & 1023;                    // spatial base

    const float* xb = x + (size_t)b * D * HW + n0;     // + d*HW + r  (uniform)

    float best[RPW];
    int   bidx[RPW];
    #pragma unroll
    for (int r = 0; r < RPW; ++r) { best[r] = 3.4e38f; bidx[r] = 0; }

    for (int cs = 0; cs < 8; ++cs) {               // code-set loop (rolled)
        const int kc = cs * 64 + lane;             // this lane's candidate code
        const float* ecol = emb + kc;              // + d*K : per-lane, coalesced

        float acc[RPW];
        #pragma unroll
        for (int r = 0; r < RPW; ++r) acc[r] = 0.f;
        float acc2 = 0.f;                          // ||e_kc||^2, built in-line

        for (int dt = 0; dt < 4; ++dt) {           // rolled: bounds code size
            #pragma unroll
            for (int dd = 0; dd < 16; ++dd) {      // unrolled
                const int d = dt * 16 + dd;
                const float ev = ecol[(size_t)d * K];     // global, lanes=k: coalesced
                acc2 = fmaf(ev, ev, acc2);
                const float* xp = xb + (size_t)d * HW;    // wave-uniform -> s_load
                #pragma unroll
                for (int r = 0; r < RPW; ++r)
                    acc[r] = fmaf(ev, xp[r], acc[r]);     // s_load_dwordx16 feed
            }
        }

        #pragma unroll
        for (int r = 0; r < RPW; ++r) {
            // score = -2*dot + ||e||^2 (fp32, same form as reference)
            float s = fmaf(-2.f, acc[r], acc2);
            if (s < best[r]) { best[r] = s; bidx[r] = kc; }   // strict <: cs ascends
        }
    }

    // --- cross-lane argmin per row: 6-step butterfly, tie -> lower index ---
    #pragma unroll
    for (int r = 0; r < RPW; ++r) {
        float bs = best[r]; int bi = bidx[r];
        #pragma unroll
        for (int off = 32; off >= 1; off >>= 1) {
            float os = __shfl_xor(bs, off);
            int   oi = __shfl_xor(bi, off);
            if (os < bs || (os == bs && oi < bi)) { bs = os; bi = oi; }
        }
        best[r] = bs; bidx[r] = bi;               // uniform across lanes now
    }

    // --- lane-select (no dynamic register indexing): row (lane&15)'s code ---
    const int rr = lane & 15;
    int kq = bidx[0];
    #pragma unroll
    for (int r = 1; r < RPW; ++r) kq = (rr == r) ? bidx[r] : kq;

    if (lane < RPW)
        __builtin_nontemporal_store((float)kq, &out_idx[r0 + lane]);

    // --- quant gather: lane -> (row = lane&15, d-sub = lane>>4) ---
    const int dsub = lane >> 4;
    float* oqb = out_q + (size_t)b * D * HW + n0 + rr;
    #pragma unroll 4
    for (int dt = 0; dt < 16; ++dt) {
        const int d = dt * 4 + dsub;
        // emb gather L2-hot; stores: 4 groups of 16 consecutive floats (64B segs)
        __builtin_nontemporal_store(emb[(size_t)d * K + kq],
                                    &oqb[(size_t)d * HW]);
    }
}

extern "C" void kernel_launch(void* const* d_in, const int* in_sizes, int n_in,
                              void* d_out, int out_size, void* d_ws, size_t ws_size,
                              hipStream_t stream)
{
    const float* x   = (const float*)d_in[0];   // 4194304 floats
    const float* emb = (const float*)d_in[1];   // 32768 floats

    float* out_q   = (float*)d_out;                     // 4194304 floats
    float* out_idx = out_q + (size_t)64 * 64 * 1024;    // 65536 floats

    // 65536 rows / (16 rows/wave * 4 waves/block) = 1024 blocks of 256
    // -> 4 blocks/CU, 4 waves/SIMD; zero LDS; VGPR ~70 by construction.
    vq_argmin_kernel<<<1024, 256, 0, stream>>>(x, emb, out_q, out_idx);
}